// Round 1
// baseline (759.216 us; speedup 1.0000x reference)
//
#include <hip/hip_runtime.h>
#include <hip/hip_bf16.h>
#include <math.h>

// Problem constants (B=2, T=1024 -> N=2048 tokens)
#define N_TOK   2048
#define C_DIM   2048
#define E_NUM   8
#define F_MOE   1408
#define F_SH    5632
#define SLOTS   4096            // N_TOK * TOPK
#define PADROWS 4224            // SLOTS + 128 slack for tile-tail reads

typedef __bf16 bf16;
typedef __bf16 bf16x8 __attribute__((ext_vector_type(8)));
typedef float  f32x4  __attribute__((ext_vector_type(4)));

__device__ __forceinline__ f32x4 mfma16(bf16x8 a, bf16x8 b, f32x4 c) {
    return __builtin_amdgcn_mfma_f32_16x16x32_bf16(a, b, c, 0, 0, 0);
}

// ---------------------------------------------------------------------------
// Router: logits = x @ gate_w^T (8), shared gate logit (1); softmax fp32,
// top-2 (lowest index on ties, like jax.lax.top_k); sigmoid gate.
// One block per token.
// ---------------------------------------------------------------------------
__global__ void router_kernel(const float* __restrict__ x,
                              const float* __restrict__ gate_w,
                              const float* __restrict__ sgate_w,
                              int* __restrict__ slotexp,
                              float* __restrict__ slotp,
                              float* __restrict__ sig)
{
    const int n   = blockIdx.x;
    const int tid = threadIdx.x;            // 256 threads
    const float* xr = x + (size_t)n * C_DIM;
    const int c0 = tid * 8;

    float xv[8];
#pragma unroll
    for (int j = 0; j < 8; ++j) xv[j] = xr[c0 + j];

    float dots[9];
#pragma unroll
    for (int e = 0; e < 9; ++e) {
        const float* wr = (e < 8) ? (gate_w + (size_t)e * C_DIM) : sgate_w;
        float p = 0.f;
#pragma unroll
        for (int j = 0; j < 8; ++j) p += xv[j] * wr[c0 + j];
#pragma unroll
        for (int off = 32; off > 0; off >>= 1) p += __shfl_down(p, off);
        dots[e] = p;
    }

    __shared__ float red[4][9];
    const int wid = tid >> 6, lane = tid & 63;
    if (lane == 0) {
#pragma unroll
        for (int e = 0; e < 9; ++e) red[wid][e] = dots[e];
    }
    __syncthreads();
    if (tid == 0) {
        float l[9];
#pragma unroll
        for (int e = 0; e < 9; ++e)
            l[e] = red[0][e] + red[1][e] + red[2][e] + red[3][e];
        float mx = l[0];
#pragma unroll
        for (int e = 1; e < 8; ++e) mx = fmaxf(mx, l[e]);
        float p[8], s = 0.f;
#pragma unroll
        for (int e = 0; e < 8; ++e) { p[e] = expf(l[e] - mx); s += p[e]; }
        const float inv = 1.f / s;
#pragma unroll
        for (int e = 0; e < 8; ++e) p[e] *= inv;
        int i1 = 0;
#pragma unroll
        for (int e = 1; e < 8; ++e) if (p[e] > p[i1]) i1 = e;
        int i2 = (i1 == 0) ? 1 : 0;
#pragma unroll
        for (int e = 0; e < 8; ++e) if (e != i1 && p[e] > p[i2]) i2 = e;
        slotexp[2 * n]     = i1;  slotp[2 * n]     = p[i1];
        slotexp[2 * n + 1] = i2;  slotp[2 * n + 1] = p[i2];
        sig[n] = 1.f / (1.f + expf(-l[8]));
    }
}

// ---------------------------------------------------------------------------
// Stable scatter: one block, 8 waves, wave e owns expert e. Ballot-scan over
// slots in order -> deterministic positions, no atomics.
// ---------------------------------------------------------------------------
__global__ void scatter_kernel(const int* __restrict__ slotexp,
                               const float* __restrict__ slotp,
                               int* __restrict__ counts, int* __restrict__ bases,
                               int* __restrict__ pos_of, int* __restrict__ row_token,
                               float* __restrict__ rowscale)
{
    const int tid = threadIdx.x;            // 512 threads = 8 waves
    const int w = tid >> 6, lane = tid & 63;
    __shared__ int cnt[E_NUM], base[E_NUM];

    int run = 0;
    for (int s0 = 0; s0 < SLOTS; s0 += 64) {
        int e = slotexp[s0 + lane];
        unsigned long long m = __ballot(e == w);
        run += __popcll(m);
    }
    if (lane == 0) cnt[w] = run;
    __syncthreads();
    if (tid == 0) {
        int b = 0;
        for (int e = 0; e < E_NUM; ++e) { base[e] = b; b += cnt[e]; }
    }
    __syncthreads();
    run = 0;
    for (int s0 = 0; s0 < SLOTS; s0 += 64) {
        const int s = s0 + lane;
        const int e = slotexp[s];
        unsigned long long m = __ballot(e == w);
        if (e == w) {
            const unsigned long long lt = (lane == 0) ? 0ull : (~0ull >> (64 - lane));
            const int pos = base[w] + run + __popcll(m & lt);
            pos_of[s]      = pos;
            row_token[pos] = s >> 1;
            rowscale[pos]  = slotp[s];
        }
        run += __popcll(m);
    }
    if (lane == 0) { counts[w] = cnt[w]; bases[w] = base[w]; }
}

// ---------------------------------------------------------------------------
// x (f32) -> Xs (bf16), elementwise, 8 elems/thread
// ---------------------------------------------------------------------------
__global__ void convert_kernel(const float* __restrict__ x, bf16* __restrict__ Xs)
{
    const size_t i = ((size_t)blockIdx.x * 256 + threadIdx.x) * 8;
    f32x4 a = *(const f32x4*)(x + i);
    f32x4 b = *(const f32x4*)(x + i + 4);
    bf16x8 o;
#pragma unroll
    for (int j = 0; j < 4; ++j) { o[j] = (bf16)a[j]; o[4 + j] = (bf16)b[j]; }
    *(bf16x8*)(Xs + i) = o;
}

// ---------------------------------------------------------------------------
// Gather token rows into per-expert-contiguous Xg. One block per position.
// ---------------------------------------------------------------------------
__global__ void gather_kernel(const bf16* __restrict__ Xs,
                              const int* __restrict__ row_token,
                              bf16* __restrict__ Xg)
{
    const int pos = blockIdx.x;
    const int t   = row_token[pos];
    const bf16x8* s = (const bf16x8*)(Xs + (size_t)t * C_DIM);
    bf16x8*       d = (bf16x8*)(Xg + (size_t)pos * C_DIM);
    d[threadIdx.x] = s[threadIdx.x];        // 256 * 8 = 2048 elems
}

// ---------------------------------------------------------------------------
// NT GEMM: out[m,n] = sum_k A[m,k] * B[n,k].  A bf16, B f32 (converted to
// bf16 while staging to LDS). 128x128 tile, BK=32, 4 waves, each wave 64x64
// (4x4 fragments of mfma_f32_16x16x32_bf16).
// DUAL:   two B matrices, epilogue H = silu(A@B1^T) * (A@B2^T) -> bf16
// !DUAL:  epilogue out = rowscale[m] * (A@B^T) -> f32
// GROUPED: blockIdx.z = expert; rows [bases[e], bases[e]+counts[e]) of A/out.
// ---------------------------------------------------------------------------
template<bool DUAL, bool GROUPED>
__global__ __launch_bounds__(256)
void gemm_nt(const bf16* __restrict__ A, int lda,
             const float* __restrict__ B1g, const float* __restrict__ B2g,
             size_t strideB,
             bf16* __restrict__ OUTh, float* __restrict__ OUTf, int ldo,
             const float* __restrict__ rowscale,
             const int* __restrict__ bases, const int* __restrict__ counts,
             int M, int N, int K)
{
    const int e    = GROUPED ? blockIdx.z : 0;
    const int base = GROUPED ? bases[e]  : 0;
    const int cnt  = GROUPED ? counts[e] : M;
    const int mt = blockIdx.y, nt = blockIdx.x;
    if (GROUPED && mt * 128 >= cnt) return;

    const float* B1 = B1g + (size_t)e * strideB;
    const float* B2 = DUAL ? (B2g + (size_t)e * strideB) : (const float*)nullptr;

    __shared__ bf16 sA [128][32];
    __shared__ bf16 sB1[128][32];
    __shared__ bf16 sB2[DUAL ? 128 : 1][32];

    const int tid = threadIdx.x;
    const int sr = tid >> 1;                 // staging row 0..127
    const int sk = (tid & 1) * 16;           // staging k offset 0/16

    const bf16*  Ap  = A  + (size_t)(base + mt * 128 + sr) * lda + sk;
    const float* B1p = B1 + (size_t)(nt * 128 + sr) * K + sk;
    const float* B2p = DUAL ? (B2 + (size_t)(nt * 128 + sr) * K + sk) : (const float*)nullptr;

    bf16x8 ra[2];
    f32x4  rb1[4], rb2[4];

    const int KT = K / 32;

    auto load_tile = [&](int kt) {
        const bf16* ap = Ap + kt * 32;
        ra[0] = *(const bf16x8*)(ap);
        ra[1] = *(const bf16x8*)(ap + 8);
        const float* bp = B1p + (size_t)kt * 32;
#pragma unroll
        for (int i = 0; i < 4; ++i) rb1[i] = *(const f32x4*)(bp + i * 4);
        if constexpr (DUAL) {
            const float* bp2 = B2p + (size_t)kt * 32;
#pragma unroll
            for (int i = 0; i < 4; ++i) rb2[i] = *(const f32x4*)(bp2 + i * 4);
        }
    };

    auto store_tile = [&]() {
        *(bf16x8*)&sA[sr][sk]     = ra[0];
        *(bf16x8*)&sA[sr][sk + 8] = ra[1];
        bf16x8 c0, c1;
#pragma unroll
        for (int i = 0; i < 2; ++i)
#pragma unroll
            for (int j = 0; j < 4; ++j) {
                c0[i * 4 + j] = (bf16)rb1[i][j];
                c1[i * 4 + j] = (bf16)rb1[2 + i][j];
            }
        *(bf16x8*)&sB1[sr][sk]     = c0;
        *(bf16x8*)&sB1[sr][sk + 8] = c1;
        if constexpr (DUAL) {
            bf16x8 d0, d1;
#pragma unroll
            for (int i = 0; i < 2; ++i)
#pragma unroll
                for (int j = 0; j < 4; ++j) {
                    d0[i * 4 + j] = (bf16)rb2[i][j];
                    d1[i * 4 + j] = (bf16)rb2[2 + i][j];
                }
            *(bf16x8*)&sB2[sr][sk]     = d0;
            *(bf16x8*)&sB2[sr][sk + 8] = d1;
        }
    };

    const int wid = tid >> 6, lane = tid & 63;
    const int wr = (wid >> 1) * 64, wc = (wid & 1) * 64;
    const int fr = lane & 15, fq = lane >> 4;

    f32x4 acc1[4][4] = {};
    f32x4 acc2[DUAL ? 4 : 1][4] = {};

    load_tile(0);
    for (int kt = 0; kt < KT; ++kt) {
        __syncthreads();                     // LDS free (prev compute done)
        store_tile();
        __syncthreads();
        if (kt + 1 < KT) load_tile(kt + 1);  // prefetch next tile into regs

        bf16x8 af[4], bfr[4];
#pragma unroll
        for (int m = 0; m < 4; ++m) af[m]  = *(const bf16x8*)&sA [wr + m * 16 + fr][fq * 8];
#pragma unroll
        for (int n = 0; n < 4; ++n) bfr[n] = *(const bf16x8*)&sB1[wc + n * 16 + fr][fq * 8];
#pragma unroll
        for (int m = 0; m < 4; ++m)
#pragma unroll
            for (int n = 0; n < 4; ++n)
                acc1[m][n] = mfma16(af[m], bfr[n], acc1[m][n]);
        if constexpr (DUAL) {
            bf16x8 bf2[4];
#pragma unroll
            for (int n = 0; n < 4; ++n) bf2[n] = *(const bf16x8*)&sB2[wc + n * 16 + fr][fq * 8];
#pragma unroll
            for (int m = 0; m < 4; ++m)
#pragma unroll
                for (int n = 0; n < 4; ++n)
                    acc2[m][n] = mfma16(af[m], bf2[n], acc2[m][n]);
        }
    }

    // Epilogue. C/D layout: col = lane&15, row = (lane>>4)*4 + j  (verified m89)
#pragma unroll
    for (int m = 0; m < 4; ++m) {
#pragma unroll
        for (int j = 0; j < 4; ++j) {
            const int r = mt * 128 + wr + m * 16 + fq * 4 + j;
            if (GROUPED && r >= cnt) continue;
            const size_t orow = (size_t)(base + r) * (size_t)ldo;
            if constexpr (DUAL) {
#pragma unroll
                for (int n = 0; n < 4; ++n) {
                    const int col = nt * 128 + wc + n * 16 + fr;
                    const float h1 = acc1[m][n][j];
                    const float h2 = acc2[m][n][j];
                    OUTh[orow + col] = (bf16)(h1 / (1.f + expf(-h1)) * h2);
                }
            } else {
                const float sc = rowscale[base + r];
#pragma unroll
                for (int n = 0; n < 4; ++n) {
                    const int col = nt * 128 + wc + n * 16 + fr;
                    OUTf[orow + col] = sc * acc1[m][n][j];
                }
            }
        }
    }
}

// ---------------------------------------------------------------------------
// y[n] = Eout[pos0(n)] + Eout[pos1(n)] + Sout[n]   (scales already applied)
// ---------------------------------------------------------------------------
__global__ void combine_kernel(const float* __restrict__ Eout,
                               const float* __restrict__ Sout,
                               const int* __restrict__ pos_of,
                               float* __restrict__ y)
{
    const int n  = blockIdx.x;
    const int p0 = pos_of[2 * n], p1 = pos_of[2 * n + 1];
    const f32x4* a = (const f32x4*)(Eout + (size_t)p0 * C_DIM);
    const f32x4* b = (const f32x4*)(Eout + (size_t)p1 * C_DIM);
    const f32x4* c = (const f32x4*)(Sout + (size_t)n * C_DIM);
    f32x4*       o = (f32x4*)(y + (size_t)n * C_DIM);
#pragma unroll
    for (int i = threadIdx.x; i < C_DIM / 4; i += 256)
        o[i] = a[i] + b[i] + c[i];
}

// ---------------------------------------------------------------------------
extern "C" void kernel_launch(void* const* d_in, const int* in_sizes, int n_in,
                              void* d_out, int out_size, void* d_ws, size_t ws_size,
                              hipStream_t stream)
{
    const float* x     = (const float*)d_in[0];
    const float* gatew = (const float*)d_in[1];
    const float* efc1  = (const float*)d_in[2];
    const float* efc2  = (const float*)d_in[3];
    const float* eproj = (const float*)d_in[4];
    const float* sfc1  = (const float*)d_in[5];
    const float* sfc2  = (const float*)d_in[6];
    const float* sproj = (const float*)d_in[7];
    const float* sgate = (const float*)d_in[8];
    float* y = (float*)d_out;

    // workspace carve-up (all 256B-aligned)
    char* w = (char*)d_ws;
    size_t off = 0;
    auto take = [&](size_t bytes) {
        char* p = w + off;
        off = (off + bytes + 255) & ~(size_t)255;
        return p;
    };
    int*   counts    = (int*)  take(E_NUM * 4);
    int*   bases     = (int*)  take(E_NUM * 4);
    int*   slotexp   = (int*)  take(SLOTS * 4);
    float* slotp     = (float*)take(SLOTS * 4);
    int*   pos_of    = (int*)  take(SLOTS * 4);
    int*   row_token = (int*)  take(PADROWS * 4);
    float* rowscale  = (float*)take(PADROWS * 4);
    float* sig       = (float*)take(N_TOK * 4);
    bf16*  Xs        = (bf16*) take((size_t)N_TOK   * C_DIM * 2);
    bf16*  Xg        = (bf16*) take((size_t)PADROWS * C_DIM * 2);
    bf16*  Hs        = (bf16*) take((size_t)N_TOK   * F_SH  * 2);
    bf16*  Hm        = (bf16*) take((size_t)PADROWS * F_MOE * 2);
    float* Sout      = (float*)take((size_t)N_TOK   * C_DIM * 4);
    float* Eout      = (float*)take((size_t)PADROWS * C_DIM * 4);
    (void)ws_size; (void)in_sizes; (void)n_in; (void)out_size;

    router_kernel<<<N_TOK, 256, 0, stream>>>(x, gatew, sgate, slotexp, slotp, sig);
    scatter_kernel<<<1, 512, 0, stream>>>(slotexp, slotp, counts, bases,
                                          pos_of, row_token, rowscale);
    convert_kernel<<<(N_TOK * C_DIM) / (256 * 8), 256, 0, stream>>>(x, Xs);
    gather_kernel<<<SLOTS, 256, 0, stream>>>(Xs, row_token, Xg);

    // shared expert: Hs = silu(Xs@fc1^T)*(Xs@fc2^T)   [2048 x 5632]
    gemm_nt<true, false><<<dim3(F_SH / 128, N_TOK / 128, 1), 256, 0, stream>>>(
        Xs, C_DIM, sfc1, sfc2, 0, Hs, nullptr, F_SH,
        nullptr, nullptr, nullptr, N_TOK, F_SH, C_DIM);

    // MoE experts (grouped): Hm = silu(Xg@fc1_e^T)*(Xg@fc2_e^T)  [cnt_e x 1408]
    gemm_nt<true, true><<<dim3(F_MOE / 128, N_TOK / 128, E_NUM), 256, 0, stream>>>(
        Xg, C_DIM, efc1, efc2, (size_t)F_MOE * C_DIM, Hm, nullptr, F_MOE,
        nullptr, bases, counts, 0, F_MOE, C_DIM);

    // shared proj: Sout = sig[n] * (Hs @ sproj^T)     [2048 x 2048]
    gemm_nt<false, false><<<dim3(C_DIM / 128, N_TOK / 128, 1), 256, 0, stream>>>(
        Hs, F_SH, sproj, nullptr, 0, nullptr, Sout, C_DIM,
        sig, nullptr, nullptr, N_TOK, C_DIM, F_SH);

    // MoE proj (grouped): Eout = p[slot] * (Hm @ proj_e^T)  [cnt_e x 2048]
    gemm_nt<false, true><<<dim3(C_DIM / 128, N_TOK / 128, E_NUM), 256, 0, stream>>>(
        Hm, F_MOE, eproj, nullptr, (size_t)C_DIM * F_MOE, nullptr, Eout, C_DIM,
        rowscale, bases, counts, 0, C_DIM, F_MOE);

    combine_kernel<<<N_TOK, 256, 0, stream>>>(Eout, Sout, pos_of, y);
}